// Round 7
// baseline (102.786 us; speedup 1.0000x reference)
//
#include <hip/hip_runtime.h>
#include <hip/hip_bf16.h>
#include <cstdint>

// HopfieldLayer: out = attn(attn(R,Y,Y), Y, Y), H=8 heads, E=64, scale 1/8.
// R7: fully wave-private flash attn. Each wave owns one S-quarter (8 tiles of
// 64) and ALL 64 q-rows of the wg (4 Q-sets) -> K ds_reads and V^T tr-reads
// feed 4x the MFMAs; KV dbuf is wave-private -> ZERO barriers in main loop;
// P^T staging lives inside the next KV buffer (no extra LDS). 4-way merge at
// end. Grid 512 wgs, 64KB LDS, 2 wg/CU.

typedef __attribute__((ext_vector_type(8))) short bf16x8;
typedef __attribute__((ext_vector_type(4))) short short4v;
typedef __attribute__((ext_vector_type(4))) float f32x4;

constexpr int B_ = 2, L_ = 2048, S_ = 2048, H_ = 8, E_ = 64, DM_ = 512;
constexpr int NTQ_ = 8; // KV tiles per S-quarter (32 total / 4)
constexpr float SCALE2 = 0.18033688011112042f; // (1/sqrt(64)) * log2(e)

__device__ __forceinline__ ushort f2bf(float a) {
  uint32_t u = __builtin_bit_cast(uint32_t, a);
  return (ushort)((u + 0x7fffu + ((u >> 16) & 1u)) >> 16); // RNE, finite inputs
}
__device__ __forceinline__ uint32_t bf16pack(float a, float b) {
  uint32_t ua = __builtin_bit_cast(uint32_t, a);
  uint32_t ub = __builtin_bit_cast(uint32_t, b);
  ua = (ua + 0x7fffu + ((ua >> 16) & 1u)) >> 16;
  ub = (ub + 0x7fffu + ((ub >> 16) & 1u)) >> 16;
  return (ua & 0xffffu) | (ub << 16);
}

__global__ void cvt_kernel(const float* __restrict__ in, ushort* __restrict__ out,
                           int n4, float mul) {
  int i = blockIdx.x * 256 + threadIdx.x;
  if (i >= n4) return;
  float4 v = reinterpret_cast<const float4*>(in)[i];
  ushort4 o;
  o.x = f2bf(v.x * mul); o.y = f2bf(v.y * mul);
  o.z = f2bf(v.z * mul); o.w = f2bf(v.w * mul);
  reinterpret_cast<ushort4*>(out)[i] = o;
}

// KV LDS tile: 64s x 64e bf16, sub-tiled for tr-reads:
//   idx(s,e) = block*64 + (s&3)*16 + (e&15),
//   block = (((s>>2)&1)*4 + (e>>4))*8 + (s>>3)
// P^T overlay (in the NEXT dbuf half, per set 512 u32):
//   u32 idx = set*512 + (nt*16+qi)*8 + g*2 + w
template <bool OUT_F32>
__global__ __launch_bounds__(256, 2) void attn_kernel(
    const ushort* __restrict__ Qb,  // bf16 [B,L,512], pre-scaled by SCALE2
    const ushort* __restrict__ Yb,  // bf16 [B,S,512]
    float* __restrict__ outF, ushort* __restrict__ outB) {
  __shared__ ushort Vsub[4][2][4096]; // [wave's S-quarter][double-buf] 64 KB

  const int tid = threadIdx.x;
  const int lane = tid & 63;
  const int wid = tid >> 6; // S-quarter this wave owns
  const int g = lane >> 4;  // 16-lane group 0..3
  const int qi = lane & 15; // this lane's q column

  const int wg = blockIdx.x;
  const int qt = wg & 31;   // L/64 = 32 q-tiles
  const int h = (wg >> 5) & 7;
  const int b = wg >> 8;

  // 4 q-sets of 16 rows; all 4 waves cover the SAME 64 q-rows
  size_t qrow[4];
#pragma unroll
  for (int set = 0; set < 4; ++set)
    qrow[set] = (size_t)(b * L_ + qt * 64 + set * 16 + qi) * DM_ + h * E_;

  bf16x8 qf[4][2]; // [set][eck], lane holds Q[q][eck*32 + g*8 .. +8]
#pragma unroll
  for (int set = 0; set < 4; ++set) {
    qf[set][0] = *reinterpret_cast<const bf16x8*>(Qb + qrow[set] + g * 8);
    qf[set][1] = *reinterpret_cast<const bf16x8*>(Qb + qrow[set] + 32 + g * 8);
  }

  f32x4 oacc[4][4]; // [set][et]
#pragma unroll
  for (int set = 0; set < 4; ++set)
#pragma unroll
    for (int et = 0; et < 4; ++et) oacc[set][et] = f32x4{0.f, 0.f, 0.f, 0.f};
  float mx[4] = {-1e30f, -1e30f, -1e30f, -1e30f};
  float ls[4] = {0.f, 0.f, 0.f, 0.f};

  // this wave's S-quarter base
  const size_t ybase = (size_t)(b * S_ + wid * 512) * DM_ + h * E_;

  // staging geometry: 64 threads stage the 8 KB tile in 8 chunks of 16 B
  // chunk i: rr = i*8 + (lane>>3), cc = lane&7
  int lidx[8];
  const ushort* gsrc[8];
#pragma unroll
  for (int i = 0; i < 8; ++i) {
    int rr = i * 8 + (lane >> 3), cc = lane & 7;
    lidx[i] = ((((rr >> 2) & 1) * 4 + (cc >> 1)) * 8 + (rr >> 3)) * 64 +
              (rr & 3) * 16 + (cc & 1) * 8;
    gsrc[i] = Yb + ybase + (size_t)rr * DM_ + cc * 8;
  }

  // ---- prologue: stage tile 0 into buffer 0 (wave-private, no barrier)
#pragma unroll
  for (int i = 0; i < 8; ++i)
    *reinterpret_cast<uint4*>(&Vsub[wid][0][lidx[i]]) =
        *reinterpret_cast<const uint4*>(gsrc[i]);

  const uint32_t vb0 = (uint32_t)(uintptr_t)(&Vsub[wid][0][0]);
  int cur = 0;

  for (int t = 0; t < NTQ_; ++t) {
    const ushort* Vc = &Vsub[wid][cur][0];
    const uint32_t vbc = vb0 + (uint32_t)(cur * 8192);
    uint32_t* Pb = (uint32_t*)&Vsub[wid][cur ^ 1][0]; // P^T overlay in next buf

    // ---- K A-frags -> registers (8 x ds_read_b128, reused by all 4 sets)
    bf16x8 kf[8]; // [nt*2+eck]
#pragma unroll
    for (int nt = 0; nt < 4; ++nt)
#pragma unroll
      for (int eck = 0; eck < 2; ++eck) {
        int s = nt * 16 + qi;
        int idx = ((((s >> 2) & 1) * 4 + (eck * 2 + (g >> 1))) * 8 + (s >> 3)) * 64 +
                  (s & 3) * 16 + (g & 1) * 8;
        kf[nt * 2 + eck] = *reinterpret_cast<const bf16x8*>(&Vc[idx]);
      }

    // ---- prefetch next tile's globals into registers (T14 issue-early)
    uint4 pf[8];
    if (t + 1 < NTQ_) {
      const size_t tadd = (size_t)(t + 1) * 64 * DM_;
#pragma unroll
      for (int i = 0; i < 8; ++i)
        pf[i] = *reinterpret_cast<const uint4*>(gsrc[i] + tadd);
    }

    // ---- per set: S^T = mfma(K, Q), online softmax, P^T -> Pb
#pragma unroll
    for (int set = 0; set < 4; ++set) {
      f32x4 st[4];
#pragma unroll
      for (int nt = 0; nt < 4; ++nt) {
        f32x4 acc = f32x4{0.f, 0.f, 0.f, 0.f};
        acc = __builtin_amdgcn_mfma_f32_16x16x32_bf16(kf[nt * 2 + 0], qf[set][0], acc, 0, 0, 0);
        acc = __builtin_amdgcn_mfma_f32_16x16x32_bf16(kf[nt * 2 + 1], qf[set][1], acc, 0, 0, 0);
        st[nt] = acc;
      }
      float tm = -1e30f;
#pragma unroll
      for (int nt = 0; nt < 4; ++nt)
#pragma unroll
        for (int r = 0; r < 4; ++r) tm = fmaxf(tm, st[nt][r]);
      tm = fmaxf(tm, __shfl_xor(tm, 16));
      tm = fmaxf(tm, __shfl_xor(tm, 32));
      if (__any(tm > mx[set] + 8.f)) { // defer-max (T13)
        float mnew = fmaxf(mx[set], tm);
        float alpha = __builtin_amdgcn_exp2f(mx[set] - mnew);
        mx[set] = mnew;
        ls[set] *= alpha;
#pragma unroll
        for (int et = 0; et < 4; ++et) oacc[set][et] *= alpha;
      }
#pragma unroll
      for (int nt = 0; nt < 4; ++nt) {
        float p0 = __builtin_amdgcn_exp2f(st[nt][0] - mx[set]);
        float p1 = __builtin_amdgcn_exp2f(st[nt][1] - mx[set]);
        float p2 = __builtin_amdgcn_exp2f(st[nt][2] - mx[set]);
        float p3 = __builtin_amdgcn_exp2f(st[nt][3] - mx[set]);
        ls[set] += (p0 + p1) + (p2 + p3);
        uint2 w;
        w.x = bf16pack(p0, p1);
        w.y = bf16pack(p2, p3);
        *reinterpret_cast<uint2*>(&Pb[set * 512 + (nt * 16 + qi) * 8 + g * 2]) = w;
      }
    }

    // ---- PV per k-chunk: tr-reads feed all 4 sets
#pragma unroll
    for (int ck = 0; ck < 2; ++ck) {
      bf16x8 pfrag[4];
#pragma unroll
      for (int set = 0; set < 4; ++set) {
        uint4 pw = *reinterpret_cast<const uint4*>(
            &Pb[set * 512 + ((2 * ck + (g >> 1)) * 16 + qi) * 8 + 4 * (g & 1)]);
        pfrag[set] = __builtin_bit_cast(bf16x8, pw);
      }
      short4v tr[4][2];
#pragma unroll
      for (int et = 0; et < 4; ++et)
#pragma unroll
        for (int pb = 0; pb < 2; ++pb) {
          uint32_t addr = vbc + (uint32_t)((((pb * 4 + et) * 8) + 4 * ck) * 128) + 8u * (uint32_t)lane;
          asm volatile("ds_read_b64_tr_b16 %0, %1" : "=v"(tr[et][pb]) : "v"(addr));
        }
      asm volatile("s_waitcnt lgkmcnt(0)" ::: "memory");
      __builtin_amdgcn_sched_barrier(0); // rule #18

#pragma unroll
      for (int et = 0; et < 4; ++et) {
        short4v lo = tr[et][0], hi = tr[et][1];
        bf16x8 vf;
        vf[0] = lo[0]; vf[1] = lo[1]; vf[2] = lo[2]; vf[3] = lo[3];
        vf[4] = hi[0]; vf[5] = hi[1]; vf[6] = hi[2]; vf[7] = hi[3];
#pragma unroll
        for (int set = 0; set < 4; ++set)
          oacc[set][et] = __builtin_amdgcn_mfma_f32_16x16x32_bf16(vf, pfrag[set], oacc[set][et], 0, 0, 0);
      }
    }

    // ---- write staged tile into next buf (overwrites P; all P reads done;
    //      same-wave DS ops are in-order, so no sync needed)
    if (t + 1 < NTQ_) {
#pragma unroll
      for (int i = 0; i < 8; ++i)
        *reinterpret_cast<uint4*>(&Vsub[wid][cur ^ 1][lidx[i]]) = pf[i];
    }
    cur ^= 1;
  }

  // ---- reduce l across g (m already wave-uniform per qi)
#pragma unroll
  for (int set = 0; set < 4; ++set) {
    ls[set] += __shfl_xor(ls[set], 16);
    ls[set] += __shfl_xor(ls[set], 32);
  }

  // ---- 4-way merge across waves via LDS
  __syncthreads(); // all wave-private work done; Vsub becomes merge scratch
  float* mrg = (float*)&Vsub[0][0][0];   // [w-1][set][et][lane][4] = 12288 f32
  float* mrgML = mrg + 12288;            // [w-1][set][{m,l}][lane] = 1536 f32

  if (wid > 0) {
    const int w = wid - 1;
#pragma unroll
    for (int set = 0; set < 4; ++set) {
#pragma unroll
      for (int et = 0; et < 4; ++et)
        *reinterpret_cast<f32x4*>(&mrg[(((w * 4 + set) * 4 + et) * 64 + lane) * 4]) =
            oacc[set][et];
      mrgML[((w * 4 + set) * 2 + 0) * 64 + lane] = mx[set];
      mrgML[((w * 4 + set) * 2 + 1) * 64 + lane] = ls[set];
    }
  }
  __syncthreads();
  if (wid == 0) {
#pragma unroll
    for (int set = 0; set < 4; ++set) {
      float m1 = mrgML[((0 * 4 + set) * 2 + 0) * 64 + lane];
      float l1 = mrgML[((0 * 4 + set) * 2 + 1) * 64 + lane];
      float m2 = mrgML[((1 * 4 + set) * 2 + 0) * 64 + lane];
      float l2 = mrgML[((1 * 4 + set) * 2 + 1) * 64 + lane];
      float m3 = mrgML[((2 * 4 + set) * 2 + 0) * 64 + lane];
      float l3 = mrgML[((2 * 4 + set) * 2 + 1) * 64 + lane];
      float M = fmaxf(fmaxf(mx[set], m1), fmaxf(m2, m3));
      float f0 = __builtin_amdgcn_exp2f(mx[set] - M);
      float f1 = __builtin_amdgcn_exp2f(m1 - M);
      float f2 = __builtin_amdgcn_exp2f(m2 - M);
      float f3 = __builtin_amdgcn_exp2f(m3 - M);
      float inv = 1.0f / (ls[set] * f0 + l1 * f1 + l2 * f2 + l3 * f3);
#pragma unroll
      for (int et = 0; et < 4; ++et) {
        f32x4 O1 = *reinterpret_cast<const f32x4*>(&mrg[(((0 * 4 + set) * 4 + et) * 64 + lane) * 4]);
        f32x4 O2 = *reinterpret_cast<const f32x4*>(&mrg[(((1 * 4 + set) * 4 + et) * 64 + lane) * 4]);
        f32x4 O3 = *reinterpret_cast<const f32x4*>(&mrg[(((2 * 4 + set) * 4 + et) * 64 + lane) * 4]);
        if constexpr (OUT_F32) {
          float4 o;
          o.x = (oacc[set][et][0] * f0 + O1[0] * f1 + O2[0] * f2 + O3[0] * f3) * inv;
          o.y = (oacc[set][et][1] * f0 + O1[1] * f1 + O2[1] * f2 + O3[1] * f3) * inv;
          o.z = (oacc[set][et][2] * f0 + O1[2] * f1 + O2[2] * f2 + O3[2] * f3) * inv;
          o.w = (oacc[set][et][3] * f0 + O1[3] * f1 + O2[3] * f2 + O3[3] * f3) * inv;
          *reinterpret_cast<float4*>(&outF[qrow[set] + et * 16 + 4 * g]) = o;
        } else {
          ushort4 o;
          o.x = f2bf((oacc[set][et][0] * f0 + O1[0] * f1 + O2[0] * f2 + O3[0] * f3) * inv * SCALE2);
          o.y = f2bf((oacc[set][et][1] * f0 + O1[1] * f1 + O2[1] * f2 + O3[1] * f3) * inv * SCALE2);
          o.z = f2bf((oacc[set][et][2] * f0 + O1[2] * f1 + O2[2] * f2 + O3[2] * f3) * inv * SCALE2);
          o.w = f2bf((oacc[set][et][3] * f0 + O1[3] * f1 + O2[3] * f2 + O3[3] * f3) * inv * SCALE2);
          *reinterpret_cast<ushort4*>(&outB[qrow[set] + et * 16 + 4 * g]) = o;
        }
      }
    }
  }
}

extern "C" void kernel_launch(void* const* d_in, const int* in_sizes, int n_in,
                              void* d_out, int out_size, void* d_ws, size_t ws_size,
                              hipStream_t stream) {
  const float* R = (const float*)d_in[0];
  const float* Y = (const float*)d_in[1];
  float* outF = (float*)d_out;

  constexpr int NE = B_ * L_ * DM_; // 2,097,152 elements per tensor
  ushort* Rb = (ushort*)d_ws;
  ushort* Yb = Rb + NE;
  ushort* q1 = Yb + NE;

  const int n4 = NE / 4;
  cvt_kernel<<<dim3((n4 + 255) / 256), 256, 0, stream>>>(R, Rb, n4, SCALE2);
  cvt_kernel<<<dim3((n4 + 255) / 256), 256, 0, stream>>>(Y, Yb, n4, 1.0f);

  const int ngrid = B_ * H_ * (L_ / 64); // 512 workgroups, 2 wg/CU
  attn_kernel<false><<<dim3(ngrid), 256, 0, stream>>>(Rb, Yb, nullptr, q1);
  attn_kernel<true><<<dim3(ngrid), 256, 0, stream>>>(q1, Yb, outF, nullptr);
}

// Round 8
// 85.631 us; speedup vs baseline: 1.2003x; 1.2003x over previous
//
#include <hip/hip_runtime.h>
#include <hip/hip_bf16.h>
#include <cstdint>

// HopfieldLayer: out = attn(attn(R,Y,Y), Y, Y), H=8 heads, E=64, scale 1/8.
// R8: wave-private flash attn at 4 wg/CU. wg = 32 q-rows (grid 1024); each
// wave owns one S-quarter as 16 tiles of 32 s (wave-private dbuf, no main-loop
// barriers), processes 2 q-sets (R6's proven register load). LDS 40KB/wg
// (KV 32KB + P 8KB) -> 16 waves/CU. Defer-max with in-branch max-reduce;
// native bf16 casts for cvt_pk. 4-way merge epilogue.

typedef __attribute__((ext_vector_type(8))) short bf16x8;
typedef __attribute__((ext_vector_type(4))) short short4v;
typedef __attribute__((ext_vector_type(4))) float f32x4;

constexpr int B_ = 2, L_ = 2048, S_ = 2048, H_ = 8, E_ = 64, DM_ = 512;
constexpr int NTQ_ = 16; // 32-s tiles per S-quarter (512 s)
constexpr float SCALE2 = 0.18033688011112042f; // (1/sqrt(64)) * log2(e)

__device__ __forceinline__ ushort f2bf(float a) {
  uint32_t u = __builtin_bit_cast(uint32_t, a);
  return (ushort)((u + 0x7fffu + ((u >> 16) & 1u)) >> 16); // RNE, finite inputs
}
__device__ __forceinline__ uint32_t pk2(float a, float b) {
  // two scalar casts -> compiler emits v_cvt_pk_bf16_f32 (m240)
  ushort u0 = __builtin_bit_cast(ushort, __float2bfloat16(a));
  ushort u1 = __builtin_bit_cast(ushort, __float2bfloat16(b));
  return (uint32_t)u0 | ((uint32_t)u1 << 16);
}

__global__ void cvt_kernel(const float* __restrict__ in, ushort* __restrict__ out,
                           int n4, float mul) {
  int i = blockIdx.x * 256 + threadIdx.x;
  if (i >= n4) return;
  float4 v = reinterpret_cast<const float4*>(in)[i];
  ushort4 o;
  o.x = f2bf(v.x * mul); o.y = f2bf(v.y * mul);
  o.z = f2bf(v.z * mul); o.w = f2bf(v.w * mul);
  reinterpret_cast<ushort4*>(out)[i] = o;
}

// KV LDS tile: 32s x 64e bf16, sub-tiled for tr-reads:
//   idx(s,e) = block*64 + (s&3)*16 + (e&15),
//   block = (((s>>2)&1)*4 + (e>>4))*4 + (s>>3)     (block 0..31)
// P region (per wave, per set, 256 u32): u32 idx = (nt*16+qi)*8 + g*2 + w
template <bool OUT_F32>
__global__ __launch_bounds__(256, 4) void attn_kernel(
    const ushort* __restrict__ Qb,  // bf16 [B,L,512], pre-scaled by SCALE2
    const ushort* __restrict__ Yb,  // bf16 [B,S,512]
    float* __restrict__ outF, ushort* __restrict__ outB) {
  __shared__ ushort Vq[4][2][2048];   // [wave][dbuf] 32 KB
  __shared__ uint32_t Pq[4][2][256];  // [wave][set]   8 KB

  const int tid = threadIdx.x;
  const int lane = tid & 63;
  const int wid = tid >> 6; // S-quarter this wave owns
  const int g = lane >> 4;  // 16-lane group 0..3
  const int qi = lane & 15; // this lane's q column

  const int wg = blockIdx.x;
  const int qt = wg & 63;   // L/32 = 64 q-tiles
  const int h = (wg >> 6) & 7;
  const int b = wg >> 9;

  // 2 q-sets of 16 rows; all 4 waves cover the SAME 32 q-rows
  size_t qrow[2];
#pragma unroll
  for (int set = 0; set < 2; ++set)
    qrow[set] = (size_t)(b * L_ + qt * 32 + set * 16 + qi) * DM_ + h * E_;

  bf16x8 qf[2][2]; // [set][eck]
#pragma unroll
  for (int set = 0; set < 2; ++set) {
    qf[set][0] = *reinterpret_cast<const bf16x8*>(Qb + qrow[set] + g * 8);
    qf[set][1] = *reinterpret_cast<const bf16x8*>(Qb + qrow[set] + 32 + g * 8);
  }

  f32x4 oacc[2][4]; // [set][et]
#pragma unroll
  for (int set = 0; set < 2; ++set)
#pragma unroll
    for (int et = 0; et < 4; ++et) oacc[set][et] = f32x4{0.f, 0.f, 0.f, 0.f};
  float mx[2] = {-1e30f, -1e30f};
  float ls[2] = {0.f, 0.f};

  // this wave's S-quarter base
  const size_t ybase = (size_t)(b * S_ + wid * 512) * DM_ + h * E_;

  // staging: 64 lanes stage the 4 KB tile in 4 chunks of 16 B
  int lidx[4];
  const ushort* gsrc[4];
#pragma unroll
  for (int i = 0; i < 4; ++i) {
    int rr = i * 8 + (lane >> 3), cc = lane & 7;
    int e0 = cc * 8;
    lidx[i] = ((((rr >> 2) & 1) * 4 + (e0 >> 4)) * 4 + (rr >> 3)) * 64 +
              (rr & 3) * 16 + (e0 & 15);
    gsrc[i] = Yb + ybase + (size_t)rr * DM_ + e0;
  }

  // K A-frag LDS element offsets: s = nt*16+qi, e0 = eck*32+8g
  int kidx[4];
#pragma unroll
  for (int nt = 0; nt < 2; ++nt)
#pragma unroll
    for (int eck = 0; eck < 2; ++eck) {
      int s = nt * 16 + qi;
      kidx[nt * 2 + eck] = ((((s >> 2) & 1) * 4 + (eck * 2 + (g >> 1))) * 4 + (s >> 3)) * 64 +
                           (s & 3) * 16 + 8 * (g & 1);
    }

  // ---- prologue: stage tile 0 into buffer 0 (wave-private, no barrier)
#pragma unroll
  for (int i = 0; i < 4; ++i)
    *reinterpret_cast<uint4*>(&Vq[wid][0][lidx[i]]) =
        *reinterpret_cast<const uint4*>(gsrc[i]);

  const uint32_t vb0 = (uint32_t)(uintptr_t)(&Vq[wid][0][0]);
  int cur = 0;

  for (int t = 0; t < NTQ_; ++t) {
    const ushort* Vc = &Vq[wid][cur][0];
    const uint32_t trbase = vb0 + (uint32_t)(cur * 4096) + 8u * (uint32_t)lane;

    // ---- K A-frags (4 ds_read_b128, each feeds both q-sets)
    bf16x8 kf[4];
#pragma unroll
    for (int i = 0; i < 4; ++i)
      kf[i] = *reinterpret_cast<const bf16x8*>(&Vc[kidx[i]]);

    // ---- prefetch next tile's globals into registers (issue-early)
    uint4 pf[4];
    if (t + 1 < NTQ_) {
      const size_t tadd = (size_t)(t + 1) * 32 * DM_;
#pragma unroll
      for (int i = 0; i < 4; ++i)
        pf[i] = *reinterpret_cast<const uint4*>(gsrc[i] + tadd);
    }

    // ---- per set: S^T = mfma(K, Q), online softmax, P -> Pq
#pragma unroll
    for (int set = 0; set < 2; ++set) {
      f32x4 st[2];
#pragma unroll
      for (int nt = 0; nt < 2; ++nt) {
        f32x4 acc = f32x4{0.f, 0.f, 0.f, 0.f};
        acc = __builtin_amdgcn_mfma_f32_16x16x32_bf16(kf[nt * 2 + 0], qf[set][0], acc, 0, 0, 0);
        acc = __builtin_amdgcn_mfma_f32_16x16x32_bf16(kf[nt * 2 + 1], qf[set][1], acc, 0, 0, 0);
        st[nt] = acc;
      }
      float tm = fmaxf(fmaxf(fmaxf(st[0][0], st[0][1]), fmaxf(st[0][2], st[0][3])),
                       fmaxf(fmaxf(st[1][0], st[1][1]), fmaxf(st[1][2], st[1][3])));
      if (__any(tm > mx[set] + 8.f)) { // defer-max: reduce+rescale only when needed
        tm = fmaxf(tm, __shfl_xor(tm, 16));
        tm = fmaxf(tm, __shfl_xor(tm, 32));
        float mnew = fmaxf(mx[set], tm);
        float alpha = __builtin_amdgcn_exp2f(mx[set] - mnew);
        mx[set] = mnew;
        ls[set] *= alpha;
#pragma unroll
        for (int et = 0; et < 4; ++et) oacc[set][et] *= alpha;
      }
#pragma unroll
      for (int nt = 0; nt < 2; ++nt) {
        float p0 = __builtin_amdgcn_exp2f(st[nt][0] - mx[set]);
        float p1 = __builtin_amdgcn_exp2f(st[nt][1] - mx[set]);
        float p2 = __builtin_amdgcn_exp2f(st[nt][2] - mx[set]);
        float p3 = __builtin_amdgcn_exp2f(st[nt][3] - mx[set]);
        ls[set] += (p0 + p1) + (p2 + p3);
        uint2 w;
        w.x = pk2(p0, p1);
        w.y = pk2(p2, p3);
        *reinterpret_cast<uint2*>(&Pq[wid][set][(nt * 16 + qi) * 8 + g * 2]) = w;
      }
    }

    // ---- PV: tr-reads feed both q-sets; K=32 covers the whole 32-s tile
    {
      bf16x8 pfrag[2];
#pragma unroll
      for (int set = 0; set < 2; ++set) {
        uint4 pw = *reinterpret_cast<const uint4*>(
            &Pq[wid][set][((g >> 1) * 16 + qi) * 8 + 4 * (g & 1)]);
        pfrag[set] = __builtin_bit_cast(bf16x8, pw);
      }
      short4v tr[4][2];
#pragma unroll
      for (int et = 0; et < 4; ++et) {
        asm volatile("ds_read_b64_tr_b16 %0, %1 offset:%2"
                     : "=v"(tr[et][0]) : "v"(trbase), "i"(et * 512));
        asm volatile("ds_read_b64_tr_b16 %0, %1 offset:%2"
                     : "=v"(tr[et][1]) : "v"(trbase), "i"((4 + et) * 512));
      }
      asm volatile("s_waitcnt lgkmcnt(0)" ::: "memory");
      __builtin_amdgcn_sched_barrier(0); // rule #18

#pragma unroll
      for (int et = 0; et < 4; ++et) {
        short4v lo = tr[et][0], hi = tr[et][1];
        bf16x8 vf;
        vf[0] = lo[0]; vf[1] = lo[1]; vf[2] = lo[2]; vf[3] = lo[3];
        vf[4] = hi[0]; vf[5] = hi[1]; vf[6] = hi[2]; vf[7] = hi[3];
#pragma unroll
        for (int set = 0; set < 2; ++set)
          oacc[set][et] = __builtin_amdgcn_mfma_f32_16x16x32_bf16(vf, pfrag[set], oacc[set][et], 0, 0, 0);
      }
    }

    // ---- write staged tile into the other buffer (wave-private, in-order DS)
    if (t + 1 < NTQ_) {
#pragma unroll
      for (int i = 0; i < 4; ++i)
        *reinterpret_cast<uint4*>(&Vq[wid][cur ^ 1][lidx[i]]) = pf[i];
    }
    cur ^= 1;
  }

  // ---- reduce l across g (m already consistent per qi by construction)
#pragma unroll
  for (int set = 0; set < 2; ++set) {
    ls[set] += __shfl_xor(ls[set], 16);
    ls[set] += __shfl_xor(ls[set], 32);
  }

  // ---- 4-way merge across waves via LDS (scratch overlays Vq)
  __syncthreads();
  float* mrg = (float*)&Vq[0][0][0];  // [w-1][set][et][lane][4] = 6144 f32
  float* mrgML = mrg + 6144;          // [w-1][set][{m,l}][lane] = 768 f32

  if (wid > 0) {
    const int w = wid - 1;
#pragma unroll
    for (int set = 0; set < 2; ++set) {
#pragma unroll
      for (int et = 0; et < 4; ++et)
        *reinterpret_cast<f32x4*>(&mrg[(((w * 2 + set) * 4 + et) * 64 + lane) * 4]) =
            oacc[set][et];
      mrgML[((w * 2 + set) * 2 + 0) * 64 + lane] = mx[set];
      mrgML[((w * 2 + set) * 2 + 1) * 64 + lane] = ls[set];
    }
  }
  __syncthreads();
  if (wid == 0) {
#pragma unroll
    for (int set = 0; set < 2; ++set) {
      float m1 = mrgML[((0 * 2 + set) * 2 + 0) * 64 + lane];
      float l1 = mrgML[((0 * 2 + set) * 2 + 1) * 64 + lane];
      float m2 = mrgML[((1 * 2 + set) * 2 + 0) * 64 + lane];
      float l2 = mrgML[((1 * 2 + set) * 2 + 1) * 64 + lane];
      float m3 = mrgML[((2 * 2 + set) * 2 + 0) * 64 + lane];
      float l3 = mrgML[((2 * 2 + set) * 2 + 1) * 64 + lane];
      float M = fmaxf(fmaxf(mx[set], m1), fmaxf(m2, m3));
      float f0 = __builtin_amdgcn_exp2f(mx[set] - M);
      float f1 = __builtin_amdgcn_exp2f(m1 - M);
      float f2 = __builtin_amdgcn_exp2f(m2 - M);
      float f3 = __builtin_amdgcn_exp2f(m3 - M);
      float inv = 1.0f / (ls[set] * f0 + l1 * f1 + l2 * f2 + l3 * f3);
#pragma unroll
      for (int et = 0; et < 4; ++et) {
        f32x4 O1 = *reinterpret_cast<const f32x4*>(&mrg[(((0 * 2 + set) * 4 + et) * 64 + lane) * 4]);
        f32x4 O2 = *reinterpret_cast<const f32x4*>(&mrg[(((1 * 2 + set) * 4 + et) * 64 + lane) * 4]);
        f32x4 O3 = *reinterpret_cast<const f32x4*>(&mrg[(((2 * 2 + set) * 4 + et) * 64 + lane) * 4]);
        if constexpr (OUT_F32) {
          float4 o;
          o.x = (oacc[set][et][0] * f0 + O1[0] * f1 + O2[0] * f2 + O3[0] * f3) * inv;
          o.y = (oacc[set][et][1] * f0 + O1[1] * f1 + O2[1] * f2 + O3[1] * f3) * inv;
          o.z = (oacc[set][et][2] * f0 + O1[2] * f1 + O2[2] * f2 + O3[2] * f3) * inv;
          o.w = (oacc[set][et][3] * f0 + O1[3] * f1 + O2[3] * f2 + O3[3] * f3) * inv;
          *reinterpret_cast<float4*>(&outF[qrow[set] + et * 16 + 4 * g]) = o;
        } else {
          ushort4 o;
          o.x = f2bf((oacc[set][et][0] * f0 + O1[0] * f1 + O2[0] * f2 + O3[0] * f3) * inv * SCALE2);
          o.y = f2bf((oacc[set][et][1] * f0 + O1[1] * f1 + O2[1] * f2 + O3[1] * f3) * inv * SCALE2);
          o.z = f2bf((oacc[set][et][2] * f0 + O1[2] * f1 + O2[2] * f2 + O3[2] * f3) * inv * SCALE2);
          o.w = f2bf((oacc[set][et][3] * f0 + O1[3] * f1 + O2[3] * f2 + O3[3] * f3) * inv * SCALE2);
          *reinterpret_cast<ushort4*>(&outB[qrow[set] + et * 16 + 4 * g]) = o;
        }
      }
    }
  }
}

extern "C" void kernel_launch(void* const* d_in, const int* in_sizes, int n_in,
                              void* d_out, int out_size, void* d_ws, size_t ws_size,
                              hipStream_t stream) {
  const float* R = (const float*)d_in[0];
  const float* Y = (const float*)d_in[1];
  float* outF = (float*)d_out;

  constexpr int NE = B_ * L_ * DM_; // 2,097,152 elements per tensor
  ushort* Rb = (ushort*)d_ws;
  ushort* Yb = Rb + NE;
  ushort* q1 = Yb + NE;

  const int n4 = NE / 4;
  cvt_kernel<<<dim3((n4 + 255) / 256), 256, 0, stream>>>(R, Rb, n4, SCALE2);
  cvt_kernel<<<dim3((n4 + 255) / 256), 256, 0, stream>>>(Y, Yb, n4, 1.0f);

  const int ngrid = B_ * H_ * (L_ / 32); // 1024 workgroups = 4 wg/CU
  attn_kernel<false><<<dim3(ngrid), 256, 0, stream>>>(Rb, Yb, nullptr, q1);
  attn_kernel<true><<<dim3(ngrid), 256, 0, stream>>>(q1, Yb, outF, nullptr);
}

// Round 9
// 77.462 us; speedup vs baseline: 1.3269x; 1.1055x over previous
//
#include <hip/hip_runtime.h>
#include <hip/hip_bf16.h>
#include <cstdint>

// HopfieldLayer: out = attn(attn(R,Y,Y), Y, Y), H=8, E=64, scale 1/8.
// R9: single fused kernel (row-independence of the update). Fixed-max softmax:
// p = exp2(s - 24) with constant 24 (safe by Cauchy-Schwarz; normalization
// cancels scale) -> no fmax tree / branch / rescale / max-shfls; -24 folded
// into MFMA C-init. Wave-private 32-s dbuf tiles + tr-reads kept verbatim from
// R8. Mid-merge broadcasts merged q (bf16, pre-scaled) via LDS; 3 barriers
// total. setprio(1) around MFMA clusters (T5).

typedef __attribute__((ext_vector_type(8))) short bf16x8;
typedef __attribute__((ext_vector_type(4))) short short4v;
typedef __attribute__((ext_vector_type(4))) float f32x4;

constexpr int B_ = 2, L_ = 2048, S_ = 2048, H_ = 8, E_ = 64, DM_ = 512;
constexpr int NTQ_ = 16; // 32-s tiles per S-quarter (512 s)
constexpr float SCALE2 = 0.18033688011112042f; // (1/sqrt(64)) * log2(e)
constexpr float FIXMAX = 24.0f;                // fixed softmax max (exp2 domain)

__device__ __forceinline__ ushort f2bf(float a) {
  uint32_t u = __builtin_bit_cast(uint32_t, a);
  return (ushort)((u + 0x7fffu + ((u >> 16) & 1u)) >> 16); // RNE, finite inputs
}
__device__ __forceinline__ uint32_t pk2(float a, float b) {
  ushort u0 = __builtin_bit_cast(ushort, __float2bfloat16(a));
  ushort u1 = __builtin_bit_cast(ushort, __float2bfloat16(b));
  return (uint32_t)u0 | ((uint32_t)u1 << 16);
}

__global__ void cvt_kernel(const float* __restrict__ in, ushort* __restrict__ out, int n4) {
  int i = blockIdx.x * 256 + threadIdx.x;
  if (i >= n4) return;
  float4 v = reinterpret_cast<const float4*>(in)[i];
  ushort4 o;
  o.x = f2bf(v.x); o.y = f2bf(v.y); o.z = f2bf(v.z); o.w = f2bf(v.w);
  reinterpret_cast<ushort4*>(out)[i] = o;
}

// KV LDS tile: 32s x 64e bf16, sub-tiled for tr-reads (R8-proven):
//   idx(s,e) = block*64 + (s&3)*16 + (e&15),
//   block = (((s>>2)&1)*4 + (e>>4))*4 + (s>>3)
// Pq[wid]: per-wave 512 u32: P staging [set][256] during main loops;
//   overlay during merges: own ml at words 0..127, q-frag chunk at words 128..383.
__global__ __launch_bounds__(256, 4) void hopfield_kernel(
    const float* __restrict__ Rf, const ushort* __restrict__ Yb,
    float* __restrict__ outF) {
  __shared__ ushort Vq[4][2][2048];  // 32 KB; merge-partial overlay (per-wave slices)
  __shared__ uint32_t Pq[4][512];    // 8 KB

  const int tid = threadIdx.x, lane = tid & 63, wid = tid >> 6;
  const int g = lane >> 4, qi = lane & 15;
  const int wg = blockIdx.x, qt = wg & 63, h = (wg >> 6) & 7, b = wg >> 9;

  size_t qbase[2];
#pragma unroll
  for (int set = 0; set < 2; ++set)
    qbase[set] = (size_t)(b * L_ + qt * 32 + set * 16 + qi) * DM_ + h * E_;

  // pass-0 Q frags: read R f32 directly, scale, pack to bf16
  bf16x8 qf[2][2];
#pragma unroll
  for (int set = 0; set < 2; ++set)
#pragma unroll
    for (int eck = 0; eck < 2; ++eck) {
      const float* s = Rf + qbase[set] + eck * 32 + 8 * g;
      float4 aa = *reinterpret_cast<const float4*>(s);
      float4 bb = *reinterpret_cast<const float4*>(s + 4);
      uint4 w;
      w.x = pk2(aa.x * SCALE2, aa.y * SCALE2);
      w.y = pk2(aa.z * SCALE2, aa.w * SCALE2);
      w.z = pk2(bb.x * SCALE2, bb.y * SCALE2);
      w.w = pk2(bb.z * SCALE2, bb.w * SCALE2);
      qf[set][eck] = __builtin_bit_cast(bf16x8, w);
    }

  const size_t ybase = (size_t)(b * S_ + wid * 512) * DM_ + h * E_;

  int lidx[4]; const ushort* gsrc[4];
#pragma unroll
  for (int i = 0; i < 4; ++i) {
    int rr = i * 8 + (lane >> 3), cc = lane & 7, e0 = cc * 8;
    lidx[i] = ((((rr >> 2) & 1) * 4 + (e0 >> 4)) * 4 + (rr >> 3)) * 64 +
              (rr & 3) * 16 + (e0 & 15);
    gsrc[i] = Yb + ybase + (size_t)rr * DM_ + e0;
  }
  int kidx[4];
#pragma unroll
  for (int nt = 0; nt < 2; ++nt)
#pragma unroll
    for (int eck = 0; eck < 2; ++eck) {
      int s = nt * 16 + qi;
      kidx[nt * 2 + eck] = ((((s >> 2) & 1) * 4 + (eck * 2 + (g >> 1))) * 4 + (s >> 3)) * 64 +
                           (s & 3) * 16 + 8 * (g & 1);
    }

  const uint32_t vb0 = (uint32_t)(uintptr_t)(&Vq[wid][0][0]);
  float* mrg = (float*)&Vq[0][0][0];
  ushort* qls = (ushort*)&Pq[0][0];

  for (int pass = 0; pass < 2; ++pass) {
    f32x4 oacc[2][4];
#pragma unroll
    for (int set = 0; set < 2; ++set)
#pragma unroll
      for (int et = 0; et < 4; ++et) oacc[set][et] = f32x4{0.f, 0.f, 0.f, 0.f};
    float ls[2] = {0.f, 0.f};

    // prologue: stage tile 0 into buffer 0 (wave-private)
#pragma unroll
    for (int i = 0; i < 4; ++i)
      *reinterpret_cast<uint4*>(&Vq[wid][0][lidx[i]]) =
          *reinterpret_cast<const uint4*>(gsrc[i]);
    int cur = 0;

    for (int t = 0; t < NTQ_; ++t) {
      const ushort* Vc = &Vq[wid][cur][0];
      const uint32_t trbase = vb0 + (uint32_t)(cur * 4096) + 8u * (uint32_t)lane;

      bf16x8 kf[4];
#pragma unroll
      for (int i = 0; i < 4; ++i)
        kf[i] = *reinterpret_cast<const bf16x8*>(&Vc[kidx[i]]);

      uint4 pf[4];
      if (t + 1 < NTQ_) {
        const size_t tadd = (size_t)(t + 1) * 32 * DM_;
#pragma unroll
        for (int i = 0; i < 4; ++i)
          pf[i] = *reinterpret_cast<const uint4*>(gsrc[i] + tadd);
      }

      // per set: S^T = mfma(K, Q) with C-init = -FIXMAX; p = exp2(st); P -> Pq
#pragma unroll
      for (int set = 0; set < 2; ++set) {
        f32x4 st[2];
        __builtin_amdgcn_s_setprio(1);
#pragma unroll
        for (int nt = 0; nt < 2; ++nt) {
          f32x4 acc = f32x4{-FIXMAX, -FIXMAX, -FIXMAX, -FIXMAX};
          acc = __builtin_amdgcn_mfma_f32_16x16x32_bf16(kf[nt * 2 + 0], qf[set][0], acc, 0, 0, 0);
          acc = __builtin_amdgcn_mfma_f32_16x16x32_bf16(kf[nt * 2 + 1], qf[set][1], acc, 0, 0, 0);
          st[nt] = acc;
        }
        __builtin_amdgcn_s_setprio(0);
#pragma unroll
        for (int nt = 0; nt < 2; ++nt) {
          float p0 = __builtin_amdgcn_exp2f(st[nt][0]);
          float p1 = __builtin_amdgcn_exp2f(st[nt][1]);
          float p2 = __builtin_amdgcn_exp2f(st[nt][2]);
          float p3 = __builtin_amdgcn_exp2f(st[nt][3]);
          ls[set] += (p0 + p1) + (p2 + p3);
          uint2 w;
          w.x = pk2(p0, p1);
          w.y = pk2(p2, p3);
          *reinterpret_cast<uint2*>(&Pq[wid][set * 256 + (nt * 16 + qi) * 8 + g * 2]) = w;
        }
      }

      // PV: tr-reads feed both q-sets
      {
        bf16x8 pfrag[2];
#pragma unroll
        for (int set = 0; set < 2; ++set) {
          uint4 pw = *reinterpret_cast<const uint4*>(
              &Pq[wid][set * 256 + ((g >> 1) * 16 + qi) * 8 + 4 * (g & 1)]);
          pfrag[set] = __builtin_bit_cast(bf16x8, pw);
        }
        short4v tr[4][2];
#pragma unroll
        for (int et = 0; et < 4; ++et) {
          asm volatile("ds_read_b64_tr_b16 %0, %1 offset:%2"
                       : "=v"(tr[et][0]) : "v"(trbase), "i"(et * 512));
          asm volatile("ds_read_b64_tr_b16 %0, %1 offset:%2"
                       : "=v"(tr[et][1]) : "v"(trbase), "i"((4 + et) * 512));
        }
        asm volatile("s_waitcnt lgkmcnt(0)" ::: "memory");
        __builtin_amdgcn_sched_barrier(0); // rule #18

        __builtin_amdgcn_s_setprio(1);
#pragma unroll
        for (int et = 0; et < 4; ++et) {
          short4v lo = tr[et][0], hi = tr[et][1];
          bf16x8 vf;
          vf[0] = lo[0]; vf[1] = lo[1]; vf[2] = lo[2]; vf[3] = lo[3];
          vf[4] = hi[0]; vf[5] = hi[1]; vf[6] = hi[2]; vf[7] = hi[3];
#pragma unroll
          for (int set = 0; set < 2; ++set)
            oacc[set][et] = __builtin_amdgcn_mfma_f32_16x16x32_bf16(vf, pfrag[set], oacc[set][et], 0, 0, 0);
        }
        __builtin_amdgcn_s_setprio(0);
      }

      if (t + 1 < NTQ_) {
#pragma unroll
        for (int i = 0; i < 4; ++i)
          *reinterpret_cast<uint4*>(&Vq[wid][cur ^ 1][lidx[i]]) = pf[i];
      }
      cur ^= 1;
    }

    // reduce l across g (sum only; fixed max)
#pragma unroll
    for (int set = 0; set < 2; ++set) {
      ls[set] += __shfl_xor(ls[set], 16);
      ls[set] += __shfl_xor(ls[set], 32);
    }

    // write own partials: O slices land exactly in own Vq[wid]; l in own Pq[wid]
    float* mlw = (float*)&Pq[wid][0];
#pragma unroll
    for (int set = 0; set < 2; ++set) {
#pragma unroll
      for (int et = 0; et < 4; ++et)
        *reinterpret_cast<f32x4*>(&mrg[(((wid * 2 + set) * 4 + et) * 64 + lane) * 4]) =
            oacc[set][et];
      mlw[set * 64 + lane] = ls[set];
    }
    __syncthreads();

    if (pass == 0) {
      // each wave merges et == wid; produce pass-1 Q frags (pre-scaled bf16)
#pragma unroll
      for (int set = 0; set < 2; ++set) {
        float lt = 0.f;
#pragma unroll
        for (int w = 0; w < 4; ++w) lt += ((float*)&Pq[w][0])[set * 64 + lane];
        float fac = SCALE2 / lt;
        f32x4 Ot = f32x4{0.f, 0.f, 0.f, 0.f};
#pragma unroll
        for (int w = 0; w < 4; ++w)
          Ot += *reinterpret_cast<const f32x4*>(&mrg[(((w * 2 + set) * 4 + wid) * 64 + lane) * 4]);
        uint2 ww;
        ww.x = pk2(Ot[0] * fac, Ot[1] * fac);
        ww.y = pk2(Ot[2] * fac, Ot[3] * fac);
        *reinterpret_cast<uint2*>(&qls[wid * 1024 + 256 + (set * 16 + qi) * 16 + 4 * g]) = ww;
      }
      __syncthreads();
#pragma unroll
      for (int set = 0; set < 2; ++set)
#pragma unroll
        for (int eck = 0; eck < 2; ++eck) {
          int et = 2 * eck + (g >> 1);
          qf[set][eck] = *reinterpret_cast<const bf16x8*>(
              &qls[et * 1024 + 256 + (set * 16 + qi) * 16 + 8 * (g & 1)]);
        }
      __syncthreads(); // frag reads complete before pass-1 P writes clobber qls
    } else {
      if (wid == 0) {
#pragma unroll
        for (int set = 0; set < 2; ++set) {
          float lt = 0.f;
#pragma unroll
          for (int w = 0; w < 4; ++w) lt += ((float*)&Pq[w][0])[set * 64 + lane];
          float inv = 1.0f / lt;
#pragma unroll
          for (int et = 0; et < 4; ++et) {
            f32x4 Ot = f32x4{0.f, 0.f, 0.f, 0.f};
#pragma unroll
            for (int w = 0; w < 4; ++w)
              Ot += *reinterpret_cast<const f32x4*>(&mrg[(((w * 2 + set) * 4 + et) * 64 + lane) * 4]);
            float4 o;
            o.x = Ot[0] * inv; o.y = Ot[1] * inv; o.z = Ot[2] * inv; o.w = Ot[3] * inv;
            *reinterpret_cast<float4*>(&outF[qbase[set] + et * 16 + 4 * g]) = o;
          }
        }
      }
    }
  }
}

extern "C" void kernel_launch(void* const* d_in, const int* in_sizes, int n_in,
                              void* d_out, int out_size, void* d_ws, size_t ws_size,
                              hipStream_t stream) {
  const float* R = (const float*)d_in[0];
  const float* Y = (const float*)d_in[1];
  float* outF = (float*)d_out;

  constexpr int NE = B_ * S_ * DM_; // 2,097,152 elements
  ushort* Yb = (ushort*)d_ws;

  const int n4 = NE / 4;
  cvt_kernel<<<dim3((n4 + 255) / 256), 256, 0, stream>>>(Y, Yb, n4);

  const int ngrid = B_ * H_ * (L_ / 32); // 1024 workgroups = 4 wg/CU
  hopfield_kernel<<<dim3(ngrid), 256, 0, stream>>>(R, Yb, outF);
}

// Round 10
// 63.037 us; speedup vs baseline: 1.6306x; 1.2288x over previous
//
#include <hip/hip_runtime.h>
#include <hip/hip_bf16.h>
#include <cstdint>

// HopfieldLayer: out = attn(attn(R,Y,Y), Y, Y), H=8, E=64, scale 1/8.
// R10: LDS-pipe offload, round 2. (1) P^T redistribution in pure VALU via
// v_permlane32/16_swap (doc semantics re-derived; R4's failure root-caused to
// raw cvt_pk asm operand order — now uses proven pk2()). (2) KV staging via
// global_load_lds DMA: linear LDS dest (chunk=lane), pre-swizzled per-lane
// global src; vmcnt(0) at loop top, next tile issued a full iteration ahead.
// Main-loop LDS ops: 4 K-reads + 8 tr-reads only. Fixed-max softmax + fused
// two-pass structure from R9. LDS 36 KB (Vq 32 + SB 4), 4 wg/CU.

typedef __attribute__((ext_vector_type(8))) short bf16x8;
typedef __attribute__((ext_vector_type(4))) short short4v;
typedef __attribute__((ext_vector_type(4))) float f32x4;

constexpr int B_ = 2, L_ = 2048, S_ = 2048, H_ = 8, E_ = 64, DM_ = 512;
constexpr int NTQ_ = 16; // 32-s tiles per S-quarter (512 s)
constexpr float SCALE2 = 0.18033688011112042f; // (1/sqrt(64)) * log2(e)
constexpr float FIXMAX = 24.0f;                // fixed softmax max (exp2 domain)

__device__ __forceinline__ ushort f2bf(float a) {
  uint32_t u = __builtin_bit_cast(uint32_t, a);
  return (ushort)((u + 0x7fffu + ((u >> 16) & 1u)) >> 16); // RNE, finite inputs
}
__device__ __forceinline__ uint32_t pk2(float a, float b) {
  ushort u0 = __builtin_bit_cast(ushort, __float2bfloat16(a));
  ushort u1 = __builtin_bit_cast(ushort, __float2bfloat16(b));
  return (uint32_t)u0 | ((uint32_t)u1 << 16);
}
__device__ __forceinline__ void dma16(const ushort* g, const ushort* l) {
  __builtin_amdgcn_global_load_lds(
      (const __attribute__((address_space(1))) uint32_t*)g,
      (__attribute__((address_space(3))) uint32_t*)l, 16, 0, 0);
}

__global__ void cvt_kernel(const float* __restrict__ in, ushort* __restrict__ out, int n4) {
  int i = blockIdx.x * 256 + threadIdx.x;
  if (i >= n4) return;
  float4 v = reinterpret_cast<const float4*>(in)[i];
  ushort4 o;
  o.x = f2bf(v.x); o.y = f2bf(v.y); o.z = f2bf(v.z); o.w = f2bf(v.w);
  reinterpret_cast<ushort4*>(out)[i] = o;
}

// KV LDS tile: 32s x 64e bf16, sub-tiled for tr-reads (R8/R9-proven):
//   idx(s,e) = block*64 + (s&3)*16 + (e&15),
//   block = (((s>>2)&1)*4 + (e>>4))*4 + (s>>3)
// DMA: LDS chunk c (16 B) at byte c*16 holds (s,e) with
//   s = (blk&3)*8 + ((blk>>4)&1)*4 + ((c>>1)&3), e0 = ((blk>>2)&3)*16 + (c&1)*8,
//   blk = c>>3.  (verified: 8c == idx(s,e0))
__global__ __launch_bounds__(256, 4) void hopfield_kernel(
    const float* __restrict__ Rf, const ushort* __restrict__ Yb,
    float* __restrict__ outF) {
  __shared__ ushort Vq[4][2][2048]; // 32 KB; merge-partial overlay (own slices)
  __shared__ uint32_t SB[1024];     // 4 KB: ml (phase 1) then q-broadcast (phase 2)

  const int tid = threadIdx.x, lane = tid & 63, wid = tid >> 6;
  const int g = lane >> 4, qi = lane & 15;
  const int wg = blockIdx.x, qt = wg & 63, h = (wg >> 6) & 7, b = wg >> 9;

  size_t qbase[2];
#pragma unroll
  for (int set = 0; set < 2; ++set)
    qbase[set] = (size_t)(b * L_ + qt * 32 + set * 16 + qi) * DM_ + h * E_;

  // pass-0 Q frags: read R f32, scale, pack to bf16
  bf16x8 qf[2][2];
#pragma unroll
  for (int set = 0; set < 2; ++set)
#pragma unroll
    for (int eck = 0; eck < 2; ++eck) {
      const float* s = Rf + qbase[set] + eck * 32 + 8 * g;
      float4 aa = *reinterpret_cast<const float4*>(s);
      float4 bb = *reinterpret_cast<const float4*>(s + 4);
      uint4 w;
      w.x = pk2(aa.x * SCALE2, aa.y * SCALE2);
      w.y = pk2(aa.z * SCALE2, aa.w * SCALE2);
      w.z = pk2(bb.x * SCALE2, bb.y * SCALE2);
      w.w = pk2(bb.z * SCALE2, bb.w * SCALE2);
      qf[set][eck] = __builtin_bit_cast(bf16x8, w);
    }

  const size_t ybase = (size_t)(b * S_ + wid * 512) * DM_ + h * E_;

  // per-lane DMA global sources (pre-swizzled to match the sub-tiled layout)
  const ushort* gdma[4];
#pragma unroll
  for (int i = 0; i < 4; ++i) {
    int c = i * 64 + lane, blk = c >> 3;
    int s = (blk & 3) * 8 + ((blk >> 4) & 1) * 4 + ((c >> 1) & 3);
    int e0 = ((blk >> 2) & 3) * 16 + (c & 1) * 8;
    gdma[i] = Yb + ybase + (size_t)s * DM_ + e0;
  }

  int kidx[4];
#pragma unroll
  for (int nt = 0; nt < 2; ++nt)
#pragma unroll
    for (int eck = 0; eck < 2; ++eck) {
      int s = nt * 16 + qi;
      kidx[nt * 2 + eck] = ((((s >> 2) & 1) * 4 + (eck * 2 + (g >> 1))) * 4 + (s >> 3)) * 64 +
                           (s & 3) * 16 + 8 * (g & 1);
    }

  const uint32_t vb0 = (uint32_t)(uintptr_t)(&Vq[wid][0][0]);
  float* mrg = (float*)&Vq[0][0][0];
  float* ml = (float*)&SB[0];
  ushort* qls = (ushort*)&SB[0];

  for (int pass = 0; pass < 2; ++pass) {
    f32x4 oacc[2][4];
#pragma unroll
    for (int set = 0; set < 2; ++set)
#pragma unroll
      for (int et = 0; et < 4; ++et) oacc[set][et] = f32x4{0.f, 0.f, 0.f, 0.f};
    float ls[2] = {0.f, 0.f};

    // prologue: DMA tile 0 into buffer 0 (wave-private slice)
#pragma unroll
    for (int i = 0; i < 4; ++i) dma16(gdma[i], &Vq[wid][0][i * 512]);
    int cur = 0;

    for (int t = 0; t < NTQ_; ++t) {
      asm volatile("s_waitcnt vmcnt(0)" ::: "memory"); // tile t resident
      if (t + 1 < NTQ_) { // issue next tile a full iteration ahead
        const size_t tadd = (size_t)(t + 1) * 32 * DM_;
#pragma unroll
        for (int i = 0; i < 4; ++i)
          dma16(gdma[i] + tadd, &Vq[wid][cur ^ 1][i * 512]);
      }

      const ushort* Vc = &Vq[wid][cur][0];
      const uint32_t trbase = vb0 + (uint32_t)(cur * 4096) + 8u * (uint32_t)lane;

      bf16x8 kf[4];
#pragma unroll
      for (int i = 0; i < 4; ++i)
        kf[i] = *reinterpret_cast<const bf16x8*>(&Vc[kidx[i]]);

      // per set: S^T = mfma(K,Q) with C-init = -FIXMAX; exp2; permlane -> pfrag
      bf16x8 pfrag[2];
#pragma unroll
      for (int set = 0; set < 2; ++set) {
        f32x4 st[2];
        __builtin_amdgcn_s_setprio(1);
#pragma unroll
        for (int nt = 0; nt < 2; ++nt) {
          f32x4 acc = f32x4{-FIXMAX, -FIXMAX, -FIXMAX, -FIXMAX};
          acc = __builtin_amdgcn_mfma_f32_16x16x32_bf16(kf[nt * 2 + 0], qf[set][0], acc, 0, 0, 0);
          acc = __builtin_amdgcn_mfma_f32_16x16x32_bf16(kf[nt * 2 + 1], qf[set][1], acc, 0, 0, 0);
          st[nt] = acc;
        }
        __builtin_amdgcn_s_setprio(0);
        float p0 = __builtin_amdgcn_exp2f(st[0][0]);
        float p1 = __builtin_amdgcn_exp2f(st[0][1]);
        float p2 = __builtin_amdgcn_exp2f(st[0][2]);
        float p3 = __builtin_amdgcn_exp2f(st[0][3]);
        float p4 = __builtin_amdgcn_exp2f(st[1][0]);
        float p5 = __builtin_amdgcn_exp2f(st[1][1]);
        float p6 = __builtin_amdgcn_exp2f(st[1][2]);
        float p7 = __builtin_amdgcn_exp2f(st[1][3]);
        ls[set] += ((p0 + p1) + (p2 + p3)) + ((p4 + p5) + (p6 + p7));
        // P^T network: rows g hold A_nt(g'); after p32+p16 swaps, a0/a1 are
        // pfrag words 0/2 (j=0,1 / 4,5), b0/b1 words 1/3 (j=2,3 / 6,7).
        uint32_t a0 = pk2(p0, p1), b0 = pk2(p2, p3);
        uint32_t a1 = pk2(p4, p5), b1 = pk2(p6, p7);
        asm("v_permlane32_swap_b32 %0, %1" : "+v"(a0), "+v"(a1));
        asm("v_permlane16_swap_b32 %0, %1" : "+v"(a0), "+v"(a1));
        asm("v_permlane32_swap_b32 %0, %1" : "+v"(b0), "+v"(b1));
        asm("v_permlane16_swap_b32 %0, %1" : "+v"(b0), "+v"(b1));
        uint4 pw;
        pw.x = a0; pw.y = b0; pw.z = a1; pw.w = b1;
        pfrag[set] = __builtin_bit_cast(bf16x8, pw);
      }

      // PV: tr-reads feed both q-sets (K=32 covers the whole tile)
      {
        short4v tr[4][2];
#pragma unroll
        for (int et = 0; et < 4; ++et) {
          asm volatile("ds_read_b64_tr_b16 %0, %1 offset:%2"
                       : "=v"(tr[et][0]) : "v"(trbase), "i"(et * 512));
          asm volatile("ds_read_b64_tr_b16 %0, %1 offset:%2"
                       : "=v"(tr[et][1]) : "v"(trbase), "i"((4 + et) * 512));
        }
        asm volatile("s_waitcnt lgkmcnt(0)" ::: "memory");
        __builtin_amdgcn_sched_barrier(0); // rule #18

        __builtin_amdgcn_s_setprio(1);
#pragma unroll
        for (int et = 0; et < 4; ++et) {
          short4v lo = tr[et][0], hi = tr[et][1];
          bf16x8 vf;
          vf[0] = lo[0]; vf[1] = lo[1]; vf[2] = lo[2]; vf[3] = lo[3];
          vf[4] = hi[0]; vf[5] = hi[1]; vf[6] = hi[2]; vf[7] = hi[3];
#pragma unroll
          for (int set = 0; set < 2; ++set)
            oacc[set][et] = __builtin_amdgcn_mfma_f32_16x16x32_bf16(vf, pfrag[set], oacc[set][et], 0, 0, 0);
        }
        __builtin_amdgcn_s_setprio(0);
      }
      cur ^= 1;
    }

    // reduce l across g (sum only; fixed max)
#pragma unroll
    for (int set = 0; set < 2; ++set) {
      ls[set] += __shfl_xor(ls[set], 16);
      ls[set] += __shfl_xor(ls[set], 32);
    }

    // write own partials: O slices land exactly in own Vq[wid]; l in own SB slots
#pragma unroll
    for (int set = 0; set < 2; ++set) {
#pragma unroll
      for (int et = 0; et < 4; ++et)
        *reinterpret_cast<f32x4*>(&mrg[(((wid * 2 + set) * 4 + et) * 64 + lane) * 4]) =
            oacc[set][et];
      ml[(wid * 2 + set) * 64 + lane] = ls[set];
    }
    __syncthreads();

    if (pass == 0) {
      // each wave merges et == wid; stash merged q (pre-scaled bf16) for broadcast
      uint2 qw[2];
#pragma unroll
      for (int set = 0; set < 2; ++set) {
        float lt = 0.f;
#pragma unroll
        for (int w = 0; w < 4; ++w) lt += ml[(w * 2 + set) * 64 + lane];
        float fac = SCALE2 / lt;
        f32x4 Ot = f32x4{0.f, 0.f, 0.f, 0.f};
#pragma unroll
        for (int w = 0; w < 4; ++w)
          Ot += *reinterpret_cast<const f32x4*>(&mrg[(((w * 2 + set) * 4 + wid) * 64 + lane) * 4]);
        qw[set].x = pk2(Ot[0] * fac, Ot[1] * fac);
        qw[set].y = pk2(Ot[2] * fac, Ot[3] * fac);
      }
      __syncthreads(); // all ml reads done before qls overwrites SB
#pragma unroll
      for (int set = 0; set < 2; ++set)
        *reinterpret_cast<uint2*>(&qls[(set * 16 + qi) * 64 + wid * 16 + 4 * g]) = qw[set];
      __syncthreads();
#pragma unroll
      for (int set = 0; set < 2; ++set)
#pragma unroll
        for (int eck = 0; eck < 2; ++eck)
          qf[set][eck] = *reinterpret_cast<const bf16x8*>(
              &qls[(set * 16 + qi) * 64 + eck * 32 + 8 * g]);
      __syncthreads(); // qf reads complete before pass-1 DMA writes Vq
    } else {
      if (wid == 0) {
#pragma unroll
        for (int set = 0; set < 2; ++set) {
          float lt = 0.f;
#pragma unroll
          for (int w = 0; w < 4; ++w) lt += ml[(w * 2 + set) * 64 + lane];
          float inv = 1.0f / lt;
#pragma unroll
          for (int et = 0; et < 4; ++et) {
            f32x4 Ot = f32x4{0.f, 0.f, 0.f, 0.f};
#pragma unroll
            for (int w = 0; w < 4; ++w)
              Ot += *reinterpret_cast<const f32x4*>(&mrg[(((w * 2 + set) * 4 + et) * 64 + lane) * 4]);
            float4 o;
            o.x = Ot[0] * inv; o.y = Ot[1] * inv; o.z = Ot[2] * inv; o.w = Ot[3] * inv;
            *reinterpret_cast<float4*>(&outF[qbase[set] + et * 16 + 4 * g]) = o;
          }
        }
      }
    }
  }
}

extern "C" void kernel_launch(void* const* d_in, const int* in_sizes, int n_in,
                              void* d_out, int out_size, void* d_ws, size_t ws_size,
                              hipStream_t stream) {
  const float* R = (const float*)d_in[0];
  const float* Y = (const float*)d_in[1];
  float* outF = (float*)d_out;

  constexpr int NE = B_ * S_ * DM_; // 2,097,152 elements
  ushort* Yb = (ushort*)d_ws;

  const int n4 = NE / 4;
  cvt_kernel<<<dim3((n4 + 255) / 256), 256, 0, stream>>>(Y, Yb, n4);

  const int ngrid = B_ * H_ * (L_ / 32); // 1024 workgroups = 4 wg/CU
  hopfield_kernel<<<dim3(ngrid), 256, 0, stream>>>(R, Yb, outF);
}